// Round 4
// baseline (148.782 us; speedup 1.0000x reference)
//
#include <hip/hip_runtime.h>
#include <math.h>

#define P 196
#define C 80
#define D 512

__device__ __constant__ float d_class_w[7] = {2.5f, 2.0f, 1.0f, 5.0f, 4.0f, 5.0f, 5.0f};
__device__ __constant__ float d_conf[49] = {
    1,3,2,1,1,2,1,
    3,1,2,1,1,1,1,
    2,2,1,1,1,1,1,
    1,1,1,1,1,1,1,
    1,1,1,1,1,1,2,
    2,1,1,1,1,1,1,
    1,1,1,1,2,1,1};

__device__ __forceinline__ float wave_sum(float v) {
  #pragma unroll
  for (int off = 32; off; off >>= 1) v += __shfl_xor(v, off, 64);
  return v;
}

__device__ __forceinline__ float wave_max(float v) {
  #pragma unroll
  for (int off = 32; off; off >>= 1) v = fmaxf(v, __shfl_xor(v, off, 64));
  return v;
}

__device__ __forceinline__ float dot4(float4 a, float4 b) {
  return a.x*b.x + a.y*b.y + a.z*b.z + a.w*b.w;
}

// One block per sample b. 1024 threads = 16 waves; wave w owns concept rank w
// (align part) and row i=w (text part). Block partials -> f[b*8 + 0..4]:
// {spos, sneg, cpos, text, cls}. No atomics, no workspace zeroing needed.
__launch_bounds__(1024)
__global__ void k_main(const float* __restrict__ cs, const int* __restrict__ labels,
                       const float* __restrict__ ps, const float* __restrict__ pf,
                       const float* __restrict__ cav, const float* __restrict__ wv,
                       const float* __restrict__ text, const int* __restrict__ tki,
                       const float* __restrict__ logits,
                       float* __restrict__ f) {
  __shared__ float scv[16][260];
  __shared__ float stx[16][260];
  __shared__ float sstext_s[16];
  __shared__ float part_s[16][4];
  __shared__ float cls_s;
  int b = blockIdx.x;
  int tid = threadIdx.x, lane = tid & 63, wave = tid >> 6;
  int l = labels[b];

  // --- cls loss for sample b (thread 0 only; ~100cy divergence, negligible)
  if (tid == 0) {
    float x[7];
    #pragma unroll
    for (int cc = 0; cc < 7; cc++) x[cc] = logits[b * 7 + cc];
    int pred = 0; float m = x[0];
    #pragma unroll
    for (int cc = 1; cc < 7; cc++) if (x[cc] > m) { m = x[cc]; pred = cc; }
    float s = 0.f;
    #pragma unroll
    for (int cc = 0; cc < 7; cc++) s += expf(x[cc] - m);
    float lse = m + logf(s);
    float logp_l = x[l] - lse;
    float ce = -logp_l;
    float pt = expf(logp_l);
    float focal = powf(1.f - pt, 2.5f);
    float maxp = expf(m - lse);
    float pen = (maxp < 0.7f) ? 1.5f : 1.f;
    cls_s = 0.25f * focal * ce * d_class_w[l] * d_conf[l * 7 + pred] * pen;
  }

  // --- Phase A: every wave redundantly finds concept of rank `wave`
  int c;
  {
    float v0 = cs[(size_t)b * C + lane];
    float v1 = (lane < C - 64) ? cs[(size_t)b * C + 64 + lane] : -INFINITY;
    c = 0;
    for (int j = 0; ; j++) {
      float m0 = v0; int i0 = lane;
      if (v1 > m0) { m0 = v1; i0 = 64 + lane; }
      float mv = wave_max(m0);
      unsigned long long mask = __ballot(m0 == mv);
      int mi = __shfl(i0, __ffsll(mask) - 1, 64);
      if (j == wave) { c = mi; break; }
      if (i0 == mi) { if (mi < 64) v0 = -INFINITY; else v1 = -INFINITY; }
    }
  }

  // --- Phase B1: 16 argmax rounds over this concept's similarity column
  // (pure VALU; patch indices collected in registers)
  int pj[16];
  {
    const float* col = ps + (size_t)b * P * C + c;
    float v0 = col[(size_t)lane * C];
    float v1 = col[(size_t)(64 + lane) * C];
    float v2 = col[(size_t)(128 + lane) * C];
    float v3 = (lane < P - 192) ? col[(size_t)(192 + lane) * C] : -INFINITY;
    #pragma unroll
    for (int j = 0; j < 16; j++) {
      float m0 = v0; int i0 = lane;
      if (v1 > m0) { m0 = v1; i0 = 64 + lane; }
      if (v2 > m0) { m0 = v2; i0 = 128 + lane; }
      if (v3 > m0) { m0 = v3; i0 = 192 + lane; }
      float mv = wave_max(m0);
      unsigned long long mask = __ballot(m0 == mv);
      int p = __shfl(i0, __ffsll(mask) - 1, 64);
      pj[j] = p;
      if (i0 == p) {
        if (p == lane) v0 = -INFINITY;
        else if (p == 64 + lane) v1 = -INFINITY;
        else if (p == 128 + lane) v2 = -INFINITY;
        else v3 = -INFINITY;
      }
    }
  }

  // --- Phase B2: gather + on-the-fly norm + mean (loads now independent)
  float4 a0 = make_float4(0, 0, 0, 0), a1 = make_float4(0, 0, 0, 0);
  {
    const float4* pfb = (const float4*)(pf + (size_t)b * P * D);
    #pragma unroll 4
    for (int j = 0; j < 16; j++) {
      const float4* row = pfb + (size_t)pj[j] * (D / 4);
      float4 r0 = row[lane], r1 = row[64 + lane];
      float ss = wave_sum(dot4(r0, r0) + dot4(r1, r1));
      float sc = 1.f / fmaxf(sqrtf(ss), 1e-12f);
      a0.x += sc * r0.x; a0.y += sc * r0.y; a0.z += sc * r0.z; a0.w += sc * r0.w;
      a1.x += sc * r1.x; a1.y += sc * r1.y; a1.z += sc * r1.z; a1.w += sc * r1.w;
    }
  }
  const float inv16 = 1.f / 16.f;
  a0.x *= inv16; a0.y *= inv16; a0.z *= inv16; a0.w *= inv16;
  a1.x *= inv16; a1.y *= inv16; a1.z *= inv16; a1.w *= inv16;

  // --- epilogue: cosine vs cav row c (scale computed locally)
  {
    const float4* crow = (const float4*)(cav + (size_t)c * D);
    float4 c0 = crow[lane], c1 = crow[64 + lane];
    float nr2 = dot4(c0, c0) + dot4(c1, c1);
    float numr = dot4(a0, c0) + dot4(a1, c1);
    float nm = dot4(a0, a0) + dot4(a1, a1);
    // w_vote row-l norm (80 floats, L2-hot)
    float wx = wv[l * C + lane];
    float wy = (lane < C - 64) ? wv[l * C + 64 + lane] : 0.f;
    float wn2 = wx * wx + wy * wy;
    #pragma unroll
    for (int off = 1; off < 64; off <<= 1) {
      nr2 += __shfl_xor(nr2, off, 64);
      numr += __shfl_xor(numr, off, 64);
      nm += __shfl_xor(nm, off, 64);
      wn2 += __shfl_xor(wn2, off, 64);
    }
    if (lane == 0) {
      float n = sqrtf(nr2);
      float csc = 1.f / (n + 1e-8f);
      float num = numr * csc;
      float ncn = n * csc;               // ||normalized cav row||
      float sim = num / fmaxf(sqrtf(nm) * ncn, 1e-8f);
      float wvs = 1.f / fmaxf(sqrtf(wn2), 1e-12f);
      float dw = wv[l * C + c] * wvs;
      float sp = 0.f, sn = 0.f, cp = 0.f;
      if (dw > 0.1f) { sp = dw * (1.f - sim); cp = 1.f; }
      else           { sn = 1.f + sim; }
      part_s[wave][0] = sp;
      part_s[wave][1] = sn;
      part_s[wave][2] = cp;
    }
  }

  // --- Phase C: text loss (16x16 sim over tki rows), fused.
  // wave w stages cav[idx_w] and text[idx_w]; thread = (i=wave, j=lane>>2, q=lane&3)
  {
    int idxw = tki[b * 16 + wave];
    const float4* cav4 = (const float4*)cav;
    const float4* text4 = (const float4*)text;
    int jj = lane >> 2, q = lane & 3;
    float dotp = 0.f, ssc = 0.f, sst = 0.f;
    #pragma unroll
    for (int ch = 0; ch < 2; ch++) {
      float4 av = cav4[(size_t)idxw * (D / 4) + ch * 64 + lane];
      float4 tv = text4[(size_t)idxw * (D / 4) + ch * 64 + lane];
      ssc += dot4(av, av);
      sst += dot4(tv, tv);
      *(float4*)&scv[wave][lane * 4] = av;
      *(float4*)&stx[wave][lane * 4] = tv;
      __syncthreads();
      #pragma unroll
      for (int k = 0; k < 16; k++) {
        float4 a = *(const float4*)&scv[wave][k * 16 + q * 4];
        float4 t4 = *(const float4*)&stx[jj][k * 16 + q * 4];
        dotp += dot4(a, t4);
      }
      __syncthreads();
    }
    ssc = wave_sum(ssc);
    sst = wave_sum(sst);
    if (lane == 0) sstext_s[wave] = sst;
    __syncthreads();
    // full dot for pair (wave, jj)
    dotp += __shfl_xor(dotp, 1, 64);
    dotp += __shfl_xor(dotp, 2, 64);
    float csc = 1.f / (sqrtf(ssc) + 1e-8f);
    float tsc = 1.f / fmaxf(sqrtf(sstext_s[jj]), 1e-12f);
    float s = dotp * csc * tsc * (1.f / 0.07f);
    s = fminf(fmaxf(s, -100.f), 100.f);
    float sd = __shfl(s, wave << 2, 64);   // diag element (i=wave, j=wave)
    float m = s;
    #pragma unroll
    for (int off = 4; off < 64; off <<= 1) m = fmaxf(m, __shfl_xor(m, off, 64));
    float e = expf(s - m);
    #pragma unroll
    for (int off = 4; off < 64; off <<= 1) e += __shfl_xor(e, off, 64);
    float lse = m + logf(e);
    if (lane == 0) part_s[wave][3] = lse - sd;
  }

  // --- block reduce + write partials
  __syncthreads();
  if (wave == 0) {
    float sp = 0.f, sn = 0.f, cp = 0.f, tx = 0.f;
    if (lane < 16) {
      sp = part_s[lane][0]; sn = part_s[lane][1];
      cp = part_s[lane][2]; tx = part_s[lane][3];
    }
    #pragma unroll
    for (int off = 1; off < 16; off <<= 1) {
      sp += __shfl_xor(sp, off, 64);
      sn += __shfl_xor(sn, off, 64);
      cp += __shfl_xor(cp, off, 64);
      tx += __shfl_xor(tx, off, 64);
    }
    if (lane == 0) {
      f[b * 8 + 0] = sp;
      f[b * 8 + 1] = sn;
      f[b * 8 + 2] = cp;
      f[b * 8 + 3] = tx;
      f[b * 8 + 4] = cls_s;
    }
  }
}

__launch_bounds__(256)
__global__ void k_final(const float* __restrict__ f, float* __restrict__ out, int B) {
  __shared__ float red[4][5];
  int tid = threadIdx.x, lane = tid & 63, wave = tid >> 6;
  float sp = 0.f, sn = 0.f, cp = 0.f, tx = 0.f, cl = 0.f;
  for (int b = tid; b < B; b += 256) {
    sp += f[b * 8 + 0];
    sn += f[b * 8 + 1];
    cp += f[b * 8 + 2];
    tx += f[b * 8 + 3];
    cl += f[b * 8 + 4];
  }
  sp = wave_sum(sp); sn = wave_sum(sn); cp = wave_sum(cp);
  tx = wave_sum(tx); cl = wave_sum(cl);
  if (lane == 0) {
    red[wave][0] = sp; red[wave][1] = sn; red[wave][2] = cp;
    red[wave][3] = tx; red[wave][4] = cl;
  }
  __syncthreads();
  if (tid == 0) {
    float SP = 0.f, SN = 0.f, CP = 0.f, TX = 0.f, CL = 0.f;
    #pragma unroll
    for (int w = 0; w < 4; w++) {
      SP += red[w][0]; SN += red[w][1]; CP += red[w][2];
      TX += red[w][3]; CL += red[w][4];
    }
    float total_pairs = (float)B * 16.f;
    float pc = fmaxf(CP, 1.f);
    float ncnt = fmaxf(total_pairs - CP, 1.f);
    float align = SP / pc + 0.1f * SN / ncnt;
    out[0] = CL / (float)B + 0.3f * align + TX / total_pairs;
  }
}

extern "C" void kernel_launch(void* const* d_in, const int* in_sizes, int n_in,
                              void* d_out, int out_size, void* d_ws, size_t ws_size,
                              hipStream_t stream) {
  const float* dl     = (const float*)d_in[0];
  const float* cs     = (const float*)d_in[1];
  const int*   labels = (const int*)d_in[2];
  const float* ps     = (const float*)d_in[3];
  const float* pf     = (const float*)d_in[4];
  const float* cav    = (const float*)d_in[5];
  const float* wv     = (const float*)d_in[6];
  const float* text   = (const float*)d_in[7];
  const int*   tki    = (const int*)d_in[8];
  float* out = (float*)d_out;
  float* f   = (float*)d_ws;
  int B = in_sizes[0] / 7;

  hipLaunchKernelGGL(k_main, dim3(B), dim3(1024), 0, stream,
                     cs, labels, ps, pf, cav, wv, text, tki, dl, f);
  hipLaunchKernelGGL(k_final, dim3(1), dim3(256), 0, stream, f, out, B);
}

// Round 5
// 93.483 us; speedup vs baseline: 1.5915x; 1.5915x over previous
//
#include <hip/hip_runtime.h>
#include <math.h>

#define P 196
#define C 80
#define D 512

// ws float-index layout
#define WS_CLS   0
#define WS_CAV   16      // 80 floats: 1/(||cav_r||+1e-8)
#define WS_TEXT  96      // 80 floats: 1/max(||text_r||,1e-12)
#define AP_BASE  1024    // align partials: (B*16) * 4 floats {sp,sn,cp,-}
#define TP_BASE  40960   // text partials: B floats

__device__ __constant__ float d_class_w[7] = {2.5f, 2.0f, 1.0f, 5.0f, 4.0f, 5.0f, 5.0f};
__device__ __constant__ float d_conf[49] = {
    1,3,2,1,1,2,1,
    3,1,2,1,1,1,1,
    2,2,1,1,1,1,1,
    1,1,1,1,1,1,1,
    1,1,1,1,1,1,2,
    2,1,1,1,1,1,1,
    1,1,1,1,2,1,1};

__device__ __forceinline__ float wave_sum(float v) {
  #pragma unroll
  for (int off = 32; off; off >>= 1) v += __shfl_xor(v, off, 64);
  return v;
}

__device__ __forceinline__ float wave_max(float v) {
  #pragma unroll
  for (int off = 32; off; off >>= 1) v = fmaxf(v, __shfl_xor(v, off, 64));
  return v;
}

__device__ __forceinline__ float dot4(float4 a, float4 b) {
  return a.x*b.x + a.y*b.y + a.z*b.z + a.w*b.w;
}

// grid 9 x 256. Blocks 0-7: cav/text row scales. Block 8: cls loss.
__launch_bounds__(256)
__global__ void k_prep(const float* __restrict__ cav, const float* __restrict__ text,
                       const float* __restrict__ logits, const int* __restrict__ labels,
                       int B, float* __restrict__ f) {
  int tid = threadIdx.x, lane = tid & 63, wave = tid >> 6;
  int blk = blockIdx.x;
  if (blk < 8) {
    for (int q = 0; q < 5; q++) {
      int r = blk * 20 + q * 4 + wave;
      const float* src = (r < 80) ? cav + (size_t)r * D : text + (size_t)(r - 80) * D;
      float4 a = ((const float4*)src)[lane];
      float4 b = ((const float4*)src)[64 + lane];
      float ss = wave_sum(dot4(a, a) + dot4(b, b));
      if (lane == 0) {
        if (r < 80) f[WS_CAV + r] = 1.f / (sqrtf(ss) + 1e-8f);
        else        f[WS_TEXT + r - 80] = 1.f / fmaxf(sqrtf(ss), 1e-12f);
      }
    }
    return;
  }
  __shared__ float part[4];
  float val = 0.f;
  for (int i = tid; i < B; i += 256) {
    float x[7];
    #pragma unroll
    for (int c = 0; c < 7; c++) x[c] = logits[i * 7 + c];
    int pred = 0; float m = x[0];
    #pragma unroll
    for (int c = 1; c < 7; c++) if (x[c] > m) { m = x[c]; pred = c; }
    float s = 0.f;
    #pragma unroll
    for (int c = 0; c < 7; c++) s += expf(x[c] - m);
    float lse = m + logf(s);
    int l = labels[i];
    float logp_l = x[l] - lse;
    float ce = -logp_l;
    float pt = expf(logp_l);
    float focal = powf(1.f - pt, 2.5f);
    float maxp = expf(m - lse);
    float pen = (maxp < 0.7f) ? 1.5f : 1.f;
    val += 0.25f * focal * ce * d_class_w[l] * d_conf[l * 7 + pred] * pen;
  }
  val = wave_sum(val);
  if (lane == 0) part[wave] = val;
  __syncthreads();
  if (tid == 0) f[WS_CLS] = part[0] + part[1] + part[2] + part[3];
}

// grid B*4, 256 threads (4 waves). Wave owns concept rank = g*4+wave.
// No LDS, no barriers. Phase A: ballot-argmax to rank. Phase B1: 16 argmax
// rounds (indices packed in 4 u32). Phase B2: paired gather with depth-2
// prefetch. Epilogue: cosine + partials to f[AP_BASE].
#define ROWP(j) (pfb + (size_t)((pw[(j)>>2] >> (((j)&3)*8)) & 0xFFu) * (D/4))
__launch_bounds__(256)
__global__ void k_main(const float* __restrict__ cs, const int* __restrict__ labels,
                       const float* __restrict__ ps, const float* __restrict__ pf,
                       const float* __restrict__ cav, const float* __restrict__ wv,
                       float* __restrict__ f, int swz) {
  int idx = blockIdx.x;
  int b, g;
  if (swz) {
    int xcd = idx & 7, rest = idx >> 3;
    g = rest & 3;
    b = (rest >> 2) * 8 + xcd;
  } else {
    b = idx >> 2; g = idx & 3;
  }
  int lane = threadIdx.x & 63, wave = threadIdx.x >> 6;
  int rank = g * 4 + wave;
  int l = labels[b];

  // Phase A: concept of rank `rank`
  int c;
  {
    float v0 = cs[(size_t)b * C + lane];
    float v1 = (lane < C - 64) ? cs[(size_t)b * C + 64 + lane] : -INFINITY;
    c = 0;
    for (int j = 0; ; j++) {
      float m0 = v0; int i0 = lane;
      if (v1 > m0) { m0 = v1; i0 = 64 + lane; }
      float mv = wave_max(m0);
      unsigned long long mask = __ballot(m0 == mv);
      int mi = __shfl(i0, __ffsll(mask) - 1, 64);
      if (j == rank) { c = mi; break; }
      if (i0 == mi) { if (mi < 64) v0 = -INFINITY; else v1 = -INFINITY; }
    }
  }

  // Phase B1: 16 patch-argmax rounds, indices packed as bytes
  unsigned pw[4] = {0u, 0u, 0u, 0u};
  {
    const float* col = ps + (size_t)b * P * C + c;
    float v0 = col[(size_t)lane * C];
    float v1 = col[(size_t)(64 + lane) * C];
    float v2 = col[(size_t)(128 + lane) * C];
    float v3 = (lane < P - 192) ? col[(size_t)(192 + lane) * C] : -INFINITY;
    #pragma unroll
    for (int j = 0; j < 16; j++) {
      float m0 = v0; int i0 = lane;
      if (v1 > m0) { m0 = v1; i0 = 64 + lane; }
      if (v2 > m0) { m0 = v2; i0 = 128 + lane; }
      if (v3 > m0) { m0 = v3; i0 = 192 + lane; }
      float mv = wave_max(m0);
      unsigned long long mask = __ballot(m0 == mv);
      int p = __shfl(i0, __ffsll(mask) - 1, 64);
      pw[j >> 2] |= (unsigned)p << ((j & 3) * 8);
      if (i0 == p) {
        if (p == lane) v0 = -INFINITY;
        else if (p == 64 + lane) v1 = -INFINITY;
        else if (p == 128 + lane) v2 = -INFINITY;
        else v3 = -INFINITY;
      }
    }
  }

  // Phase B2: paired gather + on-the-fly norm + mean, depth-2 prefetch
  float4 a0 = make_float4(0, 0, 0, 0), a1 = make_float4(0, 0, 0, 0);
  {
    const float4* pfb = (const float4*)(pf + (size_t)b * P * D);
    float4 A0 = ROWP(0)[lane], A1 = ROWP(0)[64 + lane];
    float4 B0 = ROWP(1)[lane], B1 = ROWP(1)[64 + lane];
    #pragma unroll
    for (int j = 0; j < 16; j += 2) {
      float4 N0, N1, M0, M1;
      if (j < 14) {
        const float4* rn = ROWP(j + 2);
        const float4* rm = ROWP(j + 3);
        N0 = rn[lane]; N1 = rn[64 + lane];
        M0 = rm[lane]; M1 = rm[64 + lane];
      }
      float ssA = dot4(A0, A0) + dot4(A1, A1);
      float ssB = dot4(B0, B0) + dot4(B1, B1);
      #pragma unroll
      for (int off = 32; off; off >>= 1) {
        ssA += __shfl_xor(ssA, off, 64);
        ssB += __shfl_xor(ssB, off, 64);
      }
      float scA = 1.f / fmaxf(sqrtf(ssA), 1e-12f);
      float scB = 1.f / fmaxf(sqrtf(ssB), 1e-12f);
      a0.x += scA * A0.x + scB * B0.x; a0.y += scA * A0.y + scB * B0.y;
      a0.z += scA * A0.z + scB * B0.z; a0.w += scA * A0.w + scB * B0.w;
      a1.x += scA * A1.x + scB * B1.x; a1.y += scA * A1.y + scB * B1.y;
      a1.z += scA * A1.z + scB * B1.z; a1.w += scA * A1.w + scB * B1.w;
      if (j < 14) { A0 = N0; A1 = N1; B0 = M0; B1 = M1; }
    }
  }
  const float inv16 = 1.f / 16.f;
  a0.x *= inv16; a0.y *= inv16; a0.z *= inv16; a0.w *= inv16;
  a1.x *= inv16; a1.y *= inv16; a1.z *= inv16; a1.w *= inv16;

  // epilogue: cosine vs cav row c; wv row norm computed locally
  {
    const float4* crow = (const float4*)(cav + (size_t)c * D);
    float4 c0 = crow[lane], c1 = crow[64 + lane];
    float nr2 = dot4(c0, c0) + dot4(c1, c1);
    float numr = dot4(a0, c0) + dot4(a1, c1);
    float nm = dot4(a0, a0) + dot4(a1, a1);
    float wx = wv[l * C + lane];
    float wy = (lane < C - 64) ? wv[l * C + 64 + lane] : 0.f;
    float wn2 = wx * wx + wy * wy;
    #pragma unroll
    for (int off = 1; off < 64; off <<= 1) {
      nr2 += __shfl_xor(nr2, off, 64);
      numr += __shfl_xor(numr, off, 64);
      nm += __shfl_xor(nm, off, 64);
      wn2 += __shfl_xor(wn2, off, 64);
    }
    if (lane == 0) {
      float n = sqrtf(nr2);
      float csc = 1.f / (n + 1e-8f);
      float num = numr * csc;
      float ncn = n * csc;
      float sim = num / fmaxf(sqrtf(nm) * ncn, 1e-8f);
      float wvs = 1.f / fmaxf(sqrtf(wn2), 1e-12f);
      float dw = wv[l * C + c] * wvs;
      float sp = 0.f, sn = 0.f, cp = 0.f;
      if (dw > 0.1f) { sp = dw * (1.f - sim); cp = 1.f; }
      else           { sn = 1.f + sim; }
      float* prt = f + AP_BASE + (size_t)(b * 16 + rank) * 4;
      prt[0] = sp; prt[1] = sn; prt[2] = cp;
    }
  }
}

// grid ceil(B/2) x 512: 2 samples per block. cav operand read direct from
// global (broadcast, L1-hot); only text rows staged in LDS.
#define CH 128
__launch_bounds__(512)
__global__ void k_text(const float* __restrict__ cav, const float* __restrict__ text,
                       const int* __restrict__ tki, float* __restrict__ f, int B) {
  __shared__ float stx[2][16][CH + 4];
  __shared__ int sidx[2][16];
  __shared__ float csc_s[2][16], tsc_s[2][16];
  __shared__ float rowsum[2][16];
  int tid = threadIdx.x;
  int sub = tid >> 8, tl = tid & 255;
  int b = blockIdx.x * 2 + sub;
  int bc = (b < B) ? b : (B - 1);
  if (tl < 16) {
    int ix = tki[bc * 16 + tl];
    sidx[sub][tl] = ix;
    csc_s[sub][tl] = f[WS_CAV + ix];
    tsc_s[sub][tl] = f[WS_TEXT + ix];
  }
  __syncthreads();
  int i = tl >> 4, j = tl & 15;
  const float* cr = cav + (size_t)sidx[sub][i] * D;
  float dotp = 0.f;
  for (int ch = 0; ch < D; ch += CH) {
    for (int t = tl; t < 16 * CH; t += 256) {
      int r = t >> 7, d = t & (CH - 1);
      int ix = sidx[sub][r];
      stx[sub][r][d] = text[(size_t)ix * D + ch + d];
    }
    __syncthreads();
    const float4* cr4 = (const float4*)(cr + ch);
    #pragma unroll 8
    for (int d = 0; d < CH; d += 4) {
      float4 a = cr4[d >> 2];
      float4 t4 = *(const float4*)&stx[sub][j][d];
      dotp += dot4(a, t4);
    }
    __syncthreads();
  }
  float s = dotp * csc_s[sub][i] * tsc_s[sub][j] * (1.f / 0.07f);
  s = fminf(fmaxf(s, -100.f), 100.f);
  float m = s;
  #pragma unroll
  for (int off = 1; off < 16; off <<= 1) m = fmaxf(m, __shfl_xor(m, off, 64));
  float e = expf(s - m);
  #pragma unroll
  for (int off = 1; off < 16; off <<= 1) e += __shfl_xor(e, off, 64);
  float lse = m + logf(e);
  float sd = __shfl(s, ((i & 3) << 4) | i, 64);
  if (j == 0) rowsum[sub][i] = lse - sd;
  __syncthreads();
  if (tl == 0 && b < B) {
    float acc = 0.f;
    #pragma unroll
    for (int r = 0; r < 16; r++) acc += rowsum[sub][r];
    f[TP_BASE + b] = acc;
  }
}

__launch_bounds__(256)
__global__ void k_final(const float* __restrict__ f, float* __restrict__ out, int B) {
  __shared__ float red[4][4];
  int tid = threadIdx.x, lane = tid & 63, wave = tid >> 6;
  float sp = 0.f, sn = 0.f, cp = 0.f, tx = 0.f;
  for (int t = tid; t < B * 16; t += 256) {
    const float* p = f + AP_BASE + (size_t)t * 4;
    sp += p[0]; sn += p[1]; cp += p[2];
  }
  for (int b = tid; b < B; b += 256) tx += f[TP_BASE + b];
  sp = wave_sum(sp); sn = wave_sum(sn); cp = wave_sum(cp); tx = wave_sum(tx);
  if (lane == 0) {
    red[wave][0] = sp; red[wave][1] = sn; red[wave][2] = cp; red[wave][3] = tx;
  }
  __syncthreads();
  if (tid == 0) {
    float SP = 0.f, SN = 0.f, CP = 0.f, TX = 0.f;
    #pragma unroll
    for (int w = 0; w < 4; w++) {
      SP += red[w][0]; SN += red[w][1]; CP += red[w][2]; TX += red[w][3];
    }
    float total_pairs = (float)B * 16.f;
    float pc = fmaxf(CP, 1.f);
    float ncnt = fmaxf(total_pairs - CP, 1.f);
    float align = SP / pc + 0.1f * SN / ncnt;
    out[0] = f[WS_CLS] / (float)B + 0.3f * align + TX / total_pairs;
  }
}

extern "C" void kernel_launch(void* const* d_in, const int* in_sizes, int n_in,
                              void* d_out, int out_size, void* d_ws, size_t ws_size,
                              hipStream_t stream) {
  const float* dl     = (const float*)d_in[0];
  const float* cs     = (const float*)d_in[1];
  const int*   labels = (const int*)d_in[2];
  const float* ps     = (const float*)d_in[3];
  const float* pf     = (const float*)d_in[4];
  const float* cav    = (const float*)d_in[5];
  const float* wv     = (const float*)d_in[6];
  const float* text   = (const float*)d_in[7];
  const int*   tki    = (const int*)d_in[8];
  float* out = (float*)d_out;
  float* f   = (float*)d_ws;
  int B = in_sizes[0] / 7;
  int swz = (B % 8 == 0) ? 1 : 0;

  hipLaunchKernelGGL(k_prep, dim3(9), dim3(256), 0, stream, cav, text, dl, labels, B, f);
  hipLaunchKernelGGL(k_main, dim3(B * 4), dim3(256), 0, stream,
                     cs, labels, ps, pf, cav, wv, f, swz);
  hipLaunchKernelGGL(k_text, dim3((B + 1) / 2), dim3(512), 0, stream, cav, text, tki, f, B);
  hipLaunchKernelGGL(k_final, dim3(1), dim3(256), 0, stream, f, out, B);
}

// Round 6
// 78.597 us; speedup vs baseline: 1.8930x; 1.1894x over previous
//
#include <hip/hip_runtime.h>
#include <math.h>

#define P 196
#define C 80
#define D 512

// ws float-index layout
#define WS_CLS   0
#define WS_CAV   16      // 80 floats: 1/(||cav_r||+1e-8)
#define WS_TEXT  96      // 80 floats: 1/max(||text_r||,1e-12)
#define AP_BASE  1024    // align partials: (B*16) * 4 floats {sp,sn,cp,-}
#define TP_BASE  40960   // text partials: B floats

__device__ __constant__ float d_class_w[7] = {2.5f, 2.0f, 1.0f, 5.0f, 4.0f, 5.0f, 5.0f};
__device__ __constant__ float d_conf[49] = {
    1,3,2,1,1,2,1,
    3,1,2,1,1,1,1,
    2,2,1,1,1,1,1,
    1,1,1,1,1,1,1,
    1,1,1,1,1,1,2,
    2,1,1,1,1,1,1,
    1,1,1,1,2,1,1};

__device__ __forceinline__ float wave_sum(float v) {
  #pragma unroll
  for (int off = 32; off; off >>= 1) v += __shfl_xor(v, off, 64);
  return v;
}

__device__ __forceinline__ float dot4(float4 a, float4 b) {
  return a.x*b.x + a.y*b.y + a.z*b.z + a.w*b.w;
}

// monotone map: u0 < u1  <=>  f0 < f1 (handles negatives, +-inf)
__device__ __forceinline__ unsigned mono(float v) {
  unsigned u = __float_as_uint(v);
  return u ^ (((unsigned)((int)u >> 31)) | 0x80000000u);
}

// grid 9 x 256. Blocks 0-7: cav/text row scales. Block 8: cls loss.
__launch_bounds__(256)
__global__ void k_prep(const float* __restrict__ cav, const float* __restrict__ text,
                       const float* __restrict__ logits, const int* __restrict__ labels,
                       int B, float* __restrict__ f) {
  int tid = threadIdx.x, lane = tid & 63, wave = tid >> 6;
  int blk = blockIdx.x;
  if (blk < 8) {
    for (int q = 0; q < 5; q++) {
      int r = blk * 20 + q * 4 + wave;
      const float* src = (r < 80) ? cav + (size_t)r * D : text + (size_t)(r - 80) * D;
      float4 a = ((const float4*)src)[lane];
      float4 b = ((const float4*)src)[64 + lane];
      float ss = wave_sum(dot4(a, a) + dot4(b, b));
      if (lane == 0) {
        if (r < 80) f[WS_CAV + r] = 1.f / (sqrtf(ss) + 1e-8f);
        else        f[WS_TEXT + r - 80] = 1.f / fmaxf(sqrtf(ss), 1e-12f);
      }
    }
    return;
  }
  __shared__ float part[4];
  float val = 0.f;
  for (int i = tid; i < B; i += 256) {
    float x[7];
    #pragma unroll
    for (int c = 0; c < 7; c++) x[c] = logits[i * 7 + c];
    int pred = 0; float m = x[0];
    #pragma unroll
    for (int c = 1; c < 7; c++) if (x[c] > m) { m = x[c]; pred = c; }
    float s = 0.f;
    #pragma unroll
    for (int c = 0; c < 7; c++) s += expf(x[c] - m);
    float lse = m + logf(s);
    int l = labels[i];
    float logp_l = x[l] - lse;
    float ce = -logp_l;
    float pt = expf(logp_l);
    float focal = powf(1.f - pt, 2.5f);
    float maxp = expf(m - lse);
    float pen = (maxp < 0.7f) ? 1.5f : 1.f;
    val += 0.25f * focal * ce * d_class_w[l] * d_conf[l * 7 + pred] * pen;
  }
  val = wave_sum(val);
  if (lane == 0) part[wave] = val;
  __syncthreads();
  if (tid == 0) f[WS_CLS] = part[0] + part[1] + part[2] + part[3];
}

// grid B*4, 256 threads (4 waves). Wave owns concept rank = g*4+wave.
// Selection via ballot-popcount bit-search (no DS pipe). Gather with
// depth-2 prefetch. Partials to f[AP_BASE].
#define PIDX(j) ((int)((((j) < 8) ? (pk0 >> (8 * (j))) : (pk1 >> (8 * ((j) - 8)))) & 0xFFull))
#define ROWP(j) (pfb + (size_t)PIDX(j) * (D / 4))
__launch_bounds__(256)
__global__ void k_main(const float* __restrict__ cs, const int* __restrict__ labels,
                       const float* __restrict__ ps, const float* __restrict__ pf,
                       const float* __restrict__ cav, const float* __restrict__ wv,
                       float* __restrict__ f, int swz) {
  int idx = blockIdx.x;
  int b, g;
  if (swz) {
    int xcd = idx & 7, rest = idx >> 3;
    g = rest & 3;
    b = (rest >> 2) * 8 + xcd;
  } else {
    b = idx >> 2; g = idx & 3;
  }
  int lane = threadIdx.x & 63, wave = threadIdx.x >> 6;
  int rank = g * 4 + wave;
  int l = labels[b];

  // --- Phase A: set of top-16 concepts (order-free); this wave takes the
  // rank-th element in ascending-index order.
  int c;
  {
    float v0 = cs[(size_t)b * C + lane];
    float v1 = (lane < C - 64) ? cs[(size_t)b * C + 64 + lane] : -INFINITY;
    unsigned u0 = mono(v0), u1 = mono(v1);
    unsigned prefix = 0u;
    #pragma unroll
    for (int bit = 31; bit >= 0; --bit) {
      unsigned cand = prefix | (1u << bit);
      int cnt = __popcll(__ballot(u0 >= cand)) + __popcll(__ballot(u1 >= cand));
      if (cnt >= 16) prefix = cand;
    }
    unsigned long long g0 = __ballot(u0 > prefix);
    unsigned long long g1 = __ballot(u1 > prefix);
    unsigned long long e0 = __ballot(u0 == prefix);
    unsigned long long e1 = __ballot(u1 == prefix);
    int take = 16 - __popcll(g0) - __popcll(g1);
    while (take > 0 && e0) { g0 |= e0 & (~e0 + 1ull); e0 &= e0 - 1ull; take--; }
    while (take > 0 && e1) { g1 |= e1 & (~e1 + 1ull); e1 &= e1 - 1ull; take--; }
    int p0 = __popcll(g0);
    if (rank < p0) {
      unsigned long long m = g0;
      int r = rank; while (r--) m &= m - 1ull;
      c = __ffsll(m) - 1;
    } else {
      unsigned long long m = g1;
      int r = rank - p0; while (r--) m &= m - 1ull;
      c = 64 + __ffsll(m) - 1;
    }
  }

  // --- Phase B1: top-16 patch SET for column c via the same bit-search.
  unsigned long long pk0 = 0ull, pk1 = 0ull;  // 16 packed u8 indices
  {
    const float* col = ps + (size_t)b * P * C + c;
    float v0 = col[(size_t)lane * C];
    float v1 = col[(size_t)(64 + lane) * C];
    float v2 = col[(size_t)(128 + lane) * C];
    float v3 = (lane < P - 192) ? col[(size_t)(192 + lane) * C] : -INFINITY;
    unsigned u0 = mono(v0), u1 = mono(v1), u2 = mono(v2), u3 = mono(v3);
    unsigned prefix = 0u;
    #pragma unroll
    for (int bit = 31; bit >= 0; --bit) {
      unsigned cand = prefix | (1u << bit);
      int cnt = __popcll(__ballot(u0 >= cand)) + __popcll(__ballot(u1 >= cand))
              + __popcll(__ballot(u2 >= cand)) + __popcll(__ballot(u3 >= cand));
      if (cnt >= 16) prefix = cand;
    }
    unsigned long long s0 = __ballot(u0 > prefix);
    unsigned long long s1 = __ballot(u1 > prefix);
    unsigned long long s2 = __ballot(u2 > prefix);
    unsigned long long s3 = __ballot(u3 > prefix);
    unsigned long long e0 = __ballot(u0 == prefix);
    unsigned long long e1 = __ballot(u1 == prefix);
    unsigned long long e2 = __ballot(u2 == prefix);
    unsigned long long e3 = __ballot(u3 == prefix);
    int take = 16 - __popcll(s0) - __popcll(s1) - __popcll(s2) - __popcll(s3);
    while (take > 0 && e0) { s0 |= e0 & (~e0 + 1ull); e0 &= e0 - 1ull; take--; }
    while (take > 0 && e1) { s1 |= e1 & (~e1 + 1ull); e1 &= e1 - 1ull; take--; }
    while (take > 0 && e2) { s2 |= e2 & (~e2 + 1ull); e2 &= e2 - 1ull; take--; }
    while (take > 0 && e3) { s3 |= e3 & (~e3 + 1ull); e3 &= e3 - 1ull; take--; }
    int cnt = 0;
    unsigned long long m;
    m = s0; while (m) { unsigned long long p = (unsigned long long)(__ffsll(m) - 1);
      if (cnt < 8) pk0 |= p << (8 * cnt); else pk1 |= p << (8 * (cnt - 8));
      cnt++; m &= m - 1ull; }
    m = s1; while (m) { unsigned long long p = (unsigned long long)(63 + __ffsll(m));
      if (cnt < 8) pk0 |= p << (8 * cnt); else pk1 |= p << (8 * (cnt - 8));
      cnt++; m &= m - 1ull; }
    m = s2; while (m) { unsigned long long p = (unsigned long long)(127 + __ffsll(m));
      if (cnt < 8) pk0 |= p << (8 * cnt); else pk1 |= p << (8 * (cnt - 8));
      cnt++; m &= m - 1ull; }
    m = s3; while (m) { unsigned long long p = (unsigned long long)(191 + __ffsll(m));
      if (cnt < 8) pk0 |= p << (8 * cnt); else pk1 |= p << (8 * (cnt - 8));
      cnt++; m &= m - 1ull; }
  }

  // --- Phase B2: paired gather + on-the-fly norm + mean, depth-2 prefetch
  float4 a0 = make_float4(0, 0, 0, 0), a1 = make_float4(0, 0, 0, 0);
  {
    const float4* pfb = (const float4*)(pf + (size_t)b * P * D);
    float4 A0 = ROWP(0)[lane], A1 = ROWP(0)[64 + lane];
    float4 B0 = ROWP(1)[lane], B1 = ROWP(1)[64 + lane];
    #pragma unroll
    for (int j = 0; j < 16; j += 2) {
      float4 N0, N1, M0, M1;
      if (j < 14) {
        const float4* rn = ROWP(j + 2);
        const float4* rm = ROWP(j + 3);
        N0 = rn[lane]; N1 = rn[64 + lane];
        M0 = rm[lane]; M1 = rm[64 + lane];
      }
      float ssA = dot4(A0, A0) + dot4(A1, A1);
      float ssB = dot4(B0, B0) + dot4(B1, B1);
      #pragma unroll
      for (int off = 32; off; off >>= 1) {
        ssA += __shfl_xor(ssA, off, 64);
        ssB += __shfl_xor(ssB, off, 64);
      }
      float scA = 1.f / fmaxf(sqrtf(ssA), 1e-12f);
      float scB = 1.f / fmaxf(sqrtf(ssB), 1e-12f);
      a0.x += scA * A0.x + scB * B0.x; a0.y += scA * A0.y + scB * B0.y;
      a0.z += scA * A0.z + scB * B0.z; a0.w += scA * A0.w + scB * B0.w;
      a1.x += scA * A1.x + scB * B1.x; a1.y += scA * A1.y + scB * B1.y;
      a1.z += scA * A1.z + scB * B1.z; a1.w += scA * A1.w + scB * B1.w;
      if (j < 14) { A0 = N0; A1 = N1; B0 = M0; B1 = M1; }
    }
  }
  const float inv16 = 1.f / 16.f;
  a0.x *= inv16; a0.y *= inv16; a0.z *= inv16; a0.w *= inv16;
  a1.x *= inv16; a1.y *= inv16; a1.z *= inv16; a1.w *= inv16;

  // --- epilogue: cosine vs cav row c; wv row norm computed locally
  {
    const float4* crow = (const float4*)(cav + (size_t)c * D);
    float4 c0 = crow[lane], c1 = crow[64 + lane];
    float nr2 = dot4(c0, c0) + dot4(c1, c1);
    float numr = dot4(a0, c0) + dot4(a1, c1);
    float nm = dot4(a0, a0) + dot4(a1, a1);
    float wx = wv[l * C + lane];
    float wy = (lane < C - 64) ? wv[l * C + 64 + lane] : 0.f;
    float wn2 = wx * wx + wy * wy;
    #pragma unroll
    for (int off = 1; off < 64; off <<= 1) {
      nr2 += __shfl_xor(nr2, off, 64);
      numr += __shfl_xor(numr, off, 64);
      nm += __shfl_xor(nm, off, 64);
      wn2 += __shfl_xor(wn2, off, 64);
    }
    if (lane == 0) {
      float n = sqrtf(nr2);
      float csc = 1.f / (n + 1e-8f);
      float num = numr * csc;
      float ncn = n * csc;
      float sim = num / fmaxf(sqrtf(nm) * ncn, 1e-8f);
      float wvs = 1.f / fmaxf(sqrtf(wn2), 1e-12f);
      float dw = wv[l * C + c] * wvs;
      float sp = 0.f, sn = 0.f, cp = 0.f;
      if (dw > 0.1f) { sp = dw * (1.f - sim); cp = 1.f; }
      else           { sn = 1.f + sim; }
      float* prt = f + AP_BASE + (size_t)(b * 16 + rank) * 4;
      prt[0] = sp; prt[1] = sn; prt[2] = cp;
    }
  }
}

// grid ceil(B/2) x 512: 2 samples per block. cav operand read direct from
// global (broadcast, L1-hot); only text rows staged in LDS.
#define CH 128
__launch_bounds__(512)
__global__ void k_text(const float* __restrict__ cav, const float* __restrict__ text,
                       const int* __restrict__ tki, float* __restrict__ f, int B) {
  __shared__ float stx[2][16][CH + 4];
  __shared__ int sidx[2][16];
  __shared__ float csc_s[2][16], tsc_s[2][16];
  __shared__ float rowsum[2][16];
  int tid = threadIdx.x;
  int sub = tid >> 8, tl = tid & 255;
  int b = blockIdx.x * 2 + sub;
  int bc = (b < B) ? b : (B - 1);
  if (tl < 16) {
    int ix = tki[bc * 16 + tl];
    sidx[sub][tl] = ix;
    csc_s[sub][tl] = f[WS_CAV + ix];
    tsc_s[sub][tl] = f[WS_TEXT + ix];
  }
  __syncthreads();
  int i = tl >> 4, j = tl & 15;
  const float* cr = cav + (size_t)sidx[sub][i] * D;
  float dotp = 0.f;
  for (int ch = 0; ch < D; ch += CH) {
    for (int t = tl; t < 16 * CH; t += 256) {
      int r = t >> 7, d = t & (CH - 1);
      int ix = sidx[sub][r];
      stx[sub][r][d] = text[(size_t)ix * D + ch + d];
    }
    __syncthreads();
    const float4* cr4 = (const float4*)(cr + ch);
    #pragma unroll 8
    for (int d = 0; d < CH; d += 4) {
      float4 a = cr4[d >> 2];
      float4 t4 = *(const float4*)&stx[sub][j][d];
      dotp += dot4(a, t4);
    }
    __syncthreads();
  }
  float s = dotp * csc_s[sub][i] * tsc_s[sub][j] * (1.f / 0.07f);
  s = fminf(fmaxf(s, -100.f), 100.f);
  float m = s;
  #pragma unroll
  for (int off = 1; off < 16; off <<= 1) m = fmaxf(m, __shfl_xor(m, off, 64));
  float e = expf(s - m);
  #pragma unroll
  for (int off = 1; off < 16; off <<= 1) e += __shfl_xor(e, off, 64);
  float lse = m + logf(e);
  float sd = __shfl(s, ((i & 3) << 4) | i, 64);
  if (j == 0) rowsum[sub][i] = lse - sd;
  __syncthreads();
  if (tl == 0 && b < B) {
    float acc = 0.f;
    #pragma unroll
    for (int r = 0; r < 16; r++) acc += rowsum[sub][r];
    f[TP_BASE + b] = acc;
  }
}

__launch_bounds__(256)
__global__ void k_final(const float* __restrict__ f, float* __restrict__ out, int B) {
  __shared__ float red[4][4];
  int tid = threadIdx.x, lane = tid & 63, wave = tid >> 6;
  float sp = 0.f, sn = 0.f, cp = 0.f, tx = 0.f;
  for (int t = tid; t < B * 16; t += 256) {
    const float* p = f + AP_BASE + (size_t)t * 4;
    sp += p[0]; sn += p[1]; cp += p[2];
  }
  for (int b = tid; b < B; b += 256) tx += f[TP_BASE + b];
  sp = wave_sum(sp); sn = wave_sum(sn); cp = wave_sum(cp); tx = wave_sum(tx);
  if (lane == 0) {
    red[wave][0] = sp; red[wave][1] = sn; red[wave][2] = cp; red[wave][3] = tx;
  }
  __syncthreads();
  if (tid == 0) {
    float SP = 0.f, SN = 0.f, CP = 0.f, TX = 0.f;
    #pragma unroll
    for (int w = 0; w < 4; w++) {
      SP += red[w][0]; SN += red[w][1]; CP += red[w][2]; TX += red[w][3];
    }
    float total_pairs = (float)B * 16.f;
    float pc = fmaxf(CP, 1.f);
    float ncnt = fmaxf(total_pairs - CP, 1.f);
    float align = SP / pc + 0.1f * SN / ncnt;
    out[0] = f[WS_CLS] / (float)B + 0.3f * align + TX / total_pairs;
  }
}

extern "C" void kernel_launch(void* const* d_in, const int* in_sizes, int n_in,
                              void* d_out, int out_size, void* d_ws, size_t ws_size,
                              hipStream_t stream) {
  const float* dl     = (const float*)d_in[0];
  const float* cs     = (const float*)d_in[1];
  const int*   labels = (const int*)d_in[2];
  const float* ps     = (const float*)d_in[3];
  const float* pf     = (const float*)d_in[4];
  const float* cav    = (const float*)d_in[5];
  const float* wv     = (const float*)d_in[6];
  const float* text   = (const float*)d_in[7];
  const int*   tki    = (const int*)d_in[8];
  float* out = (float*)d_out;
  float* f   = (float*)d_ws;
  int B = in_sizes[0] / 7;
  int swz = (B % 8 == 0) ? 1 : 0;

  hipLaunchKernelGGL(k_prep, dim3(9), dim3(256), 0, stream, cav, text, dl, labels, B, f);
  hipLaunchKernelGGL(k_main, dim3(B * 4), dim3(256), 0, stream,
                     cs, labels, ps, pf, cav, wv, f, swz);
  hipLaunchKernelGGL(k_text, dim3((B + 1) / 2), dim3(512), 0, stream, cav, text, tki, f, B);
  hipLaunchKernelGGL(k_final, dim3(1), dim3(256), 0, stream, f, out, B);
}

// Round 7
// 73.576 us; speedup vs baseline: 2.0222x; 1.0682x over previous
//
#include <hip/hip_runtime.h>
#include <math.h>

#define P 196
#define C 80
#define D 512
#define CH 128

// ws float-index layout
#define WS_CLS   0
#define AP_BASE  1024    // align partials: (B*16) * 4 floats {sp,sn,cp,-}
#define TP_BASE  40960   // text partials: B floats

__device__ __constant__ float d_class_w[7] = {2.5f, 2.0f, 1.0f, 5.0f, 4.0f, 5.0f, 5.0f};
__device__ __constant__ float d_conf[49] = {
    1,3,2,1,1,2,1,
    3,1,2,1,1,1,1,
    2,2,1,1,1,1,1,
    1,1,1,1,1,1,1,
    1,1,1,1,1,1,2,
    2,1,1,1,1,1,1,
    1,1,1,1,2,1,1};

__device__ __forceinline__ float wave_sum(float v) {
  #pragma unroll
  for (int off = 32; off; off >>= 1) v += __shfl_xor(v, off, 64);
  return v;
}

__device__ __forceinline__ float dot4(float4 a, float4 b) {
  return a.x*b.x + a.y*b.y + a.z*b.z + a.w*b.w;
}

// monotone map: u0 < u1  <=>  f0 < f1 (handles negatives, +-inf)
__device__ __forceinline__ unsigned mono(float v) {
  unsigned u = __float_as_uint(v);
  return u ^ (((unsigned)((int)u >> 31)) | 0x80000000u);
}

#define PIDX(j) ((int)((((j) < 8) ? (pk0 >> (8 * (j))) : (pk1 >> (8 * ((j) - 8)))) & 0xFFull))
#define ROWP(j) (pfb + (size_t)PIDX(j) * (D / 4))

// Fat kernel: blocks [0,4B) = align/main; [4B,5B) = text; [5B] = cls.
// All block roles are fully independent (no inter-block dependencies).
__launch_bounds__(256)
__global__ void k_fat(const float* __restrict__ cs, const int* __restrict__ labels,
                      const float* __restrict__ ps, const float* __restrict__ pf,
                      const float* __restrict__ cav, const float* __restrict__ wv,
                      const float* __restrict__ text, const int* __restrict__ tki,
                      const float* __restrict__ logits,
                      float* __restrict__ f, int B, int swz) {
  __shared__ float stx[16][CH + 4];
  __shared__ int sidx[16];
  __shared__ float rowsum[16];
  __shared__ float part[4];

  int bid = blockIdx.x;
  int tid = threadIdx.x, lane = tid & 63, wave = tid >> 6;

  if (bid < 4 * B) {
    // ================= MAIN (align) path =================
    int b, g;
    if (swz) {
      int xcd = bid & 7, rest = bid >> 3;
      g = rest & 3;
      b = (rest >> 2) * 8 + xcd;
    } else {
      b = bid >> 2; g = bid & 3;
    }
    int rank = g * 4 + wave;
    int l = labels[b];

    // --- Phase A: set of top-16 concepts (order-free); wave takes rank-th.
    int c;
    {
      float v0 = cs[(size_t)b * C + lane];
      float v1 = (lane < C - 64) ? cs[(size_t)b * C + 64 + lane] : -INFINITY;
      unsigned u0 = mono(v0), u1 = mono(v1);
      unsigned prefix = 0u;
      #pragma unroll
      for (int bit = 31; bit >= 0; --bit) {
        unsigned cand = prefix | (1u << bit);
        int cnt = __popcll(__ballot(u0 >= cand)) + __popcll(__ballot(u1 >= cand));
        if (cnt >= 16) prefix = cand;
      }
      unsigned long long g0 = __ballot(u0 > prefix);
      unsigned long long g1 = __ballot(u1 > prefix);
      unsigned long long e0 = __ballot(u0 == prefix);
      unsigned long long e1 = __ballot(u1 == prefix);
      int take = 16 - __popcll(g0) - __popcll(g1);
      while (take > 0 && e0) { g0 |= e0 & (~e0 + 1ull); e0 &= e0 - 1ull; take--; }
      while (take > 0 && e1) { g1 |= e1 & (~e1 + 1ull); e1 &= e1 - 1ull; take--; }
      int p0 = __popcll(g0);
      if (rank < p0) {
        unsigned long long m = g0;
        int r = rank; while (r--) m &= m - 1ull;
        c = __ffsll(m) - 1;
      } else {
        unsigned long long m = g1;
        int r = rank - p0; while (r--) m &= m - 1ull;
        c = 64 + __ffsll(m) - 1;
      }
    }

    // --- Phase B1: top-16 patch SET for column c via the same bit-search.
    unsigned long long pk0 = 0ull, pk1 = 0ull;
    {
      const float* col = ps + (size_t)b * P * C + c;
      float v0 = col[(size_t)lane * C];
      float v1 = col[(size_t)(64 + lane) * C];
      float v2 = col[(size_t)(128 + lane) * C];
      float v3 = (lane < P - 192) ? col[(size_t)(192 + lane) * C] : -INFINITY;
      unsigned u0 = mono(v0), u1 = mono(v1), u2 = mono(v2), u3 = mono(v3);
      unsigned prefix = 0u;
      #pragma unroll
      for (int bit = 31; bit >= 0; --bit) {
        unsigned cand = prefix | (1u << bit);
        int cnt = __popcll(__ballot(u0 >= cand)) + __popcll(__ballot(u1 >= cand))
                + __popcll(__ballot(u2 >= cand)) + __popcll(__ballot(u3 >= cand));
        if (cnt >= 16) prefix = cand;
      }
      unsigned long long s0 = __ballot(u0 > prefix);
      unsigned long long s1 = __ballot(u1 > prefix);
      unsigned long long s2 = __ballot(u2 > prefix);
      unsigned long long s3 = __ballot(u3 > prefix);
      unsigned long long e0 = __ballot(u0 == prefix);
      unsigned long long e1 = __ballot(u1 == prefix);
      unsigned long long e2 = __ballot(u2 == prefix);
      unsigned long long e3 = __ballot(u3 == prefix);
      int take = 16 - __popcll(s0) - __popcll(s1) - __popcll(s2) - __popcll(s3);
      while (take > 0 && e0) { s0 |= e0 & (~e0 + 1ull); e0 &= e0 - 1ull; take--; }
      while (take > 0 && e1) { s1 |= e1 & (~e1 + 1ull); e1 &= e1 - 1ull; take--; }
      while (take > 0 && e2) { s2 |= e2 & (~e2 + 1ull); e2 &= e2 - 1ull; take--; }
      while (take > 0 && e3) { s3 |= e3 & (~e3 + 1ull); e3 &= e3 - 1ull; take--; }
      int cnt = 0;
      unsigned long long m;
      m = s0; while (m) { unsigned long long p = (unsigned long long)(__ffsll(m) - 1);
        if (cnt < 8) pk0 |= p << (8 * cnt); else pk1 |= p << (8 * (cnt - 8));
        cnt++; m &= m - 1ull; }
      m = s1; while (m) { unsigned long long p = (unsigned long long)(63 + __ffsll(m));
        if (cnt < 8) pk0 |= p << (8 * cnt); else pk1 |= p << (8 * (cnt - 8));
        cnt++; m &= m - 1ull; }
      m = s2; while (m) { unsigned long long p = (unsigned long long)(127 + __ffsll(m));
        if (cnt < 8) pk0 |= p << (8 * cnt); else pk1 |= p << (8 * (cnt - 8));
        cnt++; m &= m - 1ull; }
      m = s3; while (m) { unsigned long long p = (unsigned long long)(191 + __ffsll(m));
        if (cnt < 8) pk0 |= p << (8 * cnt); else pk1 |= p << (8 * (cnt - 8));
        cnt++; m &= m - 1ull; }
    }

    // --- Phase B2: paired gather + on-the-fly norm + mean, depth-2 prefetch
    float4 a0 = make_float4(0, 0, 0, 0), a1 = make_float4(0, 0, 0, 0);
    {
      const float4* pfb = (const float4*)(pf + (size_t)b * P * D);
      float4 A0 = ROWP(0)[lane], A1 = ROWP(0)[64 + lane];
      float4 B0 = ROWP(1)[lane], B1 = ROWP(1)[64 + lane];
      #pragma unroll
      for (int j = 0; j < 16; j += 2) {
        float4 N0, N1, M0, M1;
        if (j < 14) {
          const float4* rn = ROWP(j + 2);
          const float4* rm = ROWP(j + 3);
          N0 = rn[lane]; N1 = rn[64 + lane];
          M0 = rm[lane]; M1 = rm[64 + lane];
        }
        float ssA = dot4(A0, A0) + dot4(A1, A1);
        float ssB = dot4(B0, B0) + dot4(B1, B1);
        #pragma unroll
        for (int off = 32; off; off >>= 1) {
          ssA += __shfl_xor(ssA, off, 64);
          ssB += __shfl_xor(ssB, off, 64);
        }
        float scA = 1.f / fmaxf(sqrtf(ssA), 1e-12f);
        float scB = 1.f / fmaxf(sqrtf(ssB), 1e-12f);
        a0.x += scA * A0.x + scB * B0.x; a0.y += scA * A0.y + scB * B0.y;
        a0.z += scA * A0.z + scB * B0.z; a0.w += scA * A0.w + scB * B0.w;
        a1.x += scA * A1.x + scB * B1.x; a1.y += scA * A1.y + scB * B1.y;
        a1.z += scA * A1.z + scB * B1.z; a1.w += scA * A1.w + scB * B1.w;
        if (j < 14) { A0 = N0; A1 = N1; B0 = M0; B1 = M1; }
      }
    }
    const float inv16 = 1.f / 16.f;
    a0.x *= inv16; a0.y *= inv16; a0.z *= inv16; a0.w *= inv16;
    a1.x *= inv16; a1.y *= inv16; a1.z *= inv16; a1.w *= inv16;

    // --- epilogue: cosine vs cav row c; wv row norm computed locally
    {
      const float4* crow = (const float4*)(cav + (size_t)c * D);
      float4 c0 = crow[lane], c1 = crow[64 + lane];
      float nr2 = dot4(c0, c0) + dot4(c1, c1);
      float numr = dot4(a0, c0) + dot4(a1, c1);
      float nm = dot4(a0, a0) + dot4(a1, a1);
      float wx = wv[l * C + lane];
      float wy = (lane < C - 64) ? wv[l * C + 64 + lane] : 0.f;
      float wn2 = wx * wx + wy * wy;
      #pragma unroll
      for (int off = 1; off < 64; off <<= 1) {
        nr2 += __shfl_xor(nr2, off, 64);
        numr += __shfl_xor(numr, off, 64);
        nm += __shfl_xor(nm, off, 64);
        wn2 += __shfl_xor(wn2, off, 64);
      }
      if (lane == 0) {
        float n = sqrtf(nr2);
        float csc = 1.f / (n + 1e-8f);
        float num = numr * csc;
        float ncn = n * csc;
        float sim = num / fmaxf(sqrtf(nm) * ncn, 1e-8f);
        float wvs = 1.f / fmaxf(sqrtf(wn2), 1e-12f);
        float dw = wv[l * C + c] * wvs;
        float sp = 0.f, sn = 0.f, cp = 0.f;
        if (dw > 0.1f) { sp = dw * (1.f - sim); cp = 1.f; }
        else           { sn = 1.f + sim; }
        float* prt = f + AP_BASE + (size_t)(b * 16 + rank) * 4;
        prt[0] = sp; prt[1] = sn; prt[2] = cp;
      }
    }
    return;
  }

  if (bid < 5 * B) {
    // ================= TEXT path (1 sample/block, self-computed norms) =====
    int b = bid - 4 * B;
    if (tid < 16) sidx[tid] = tki[b * 16 + tid];
    __syncthreads();
    int i = tid >> 4, j = tid & 15;
    const float* cr = cav + (size_t)sidx[i] * D;
    float dotp = 0.f, ssc = 0.f, sst = 0.f;
    for (int ch = 0; ch < D; ch += CH) {
      for (int t = tid; t < 16 * CH; t += 256) {
        int r = t >> 7, d = t & (CH - 1);
        stx[r][d] = text[(size_t)sidx[r] * D + ch + d];
      }
      __syncthreads();
      const float4* cr4 = (const float4*)(cr + ch);
      #pragma unroll 8
      for (int d = 0; d < CH; d += 4) {
        float4 a = cr4[d >> 2];
        float4 t4 = *(const float4*)&stx[j][d];
        dotp += dot4(a, t4);
        ssc += dot4(a, a);
        sst += dot4(t4, t4);
      }
      __syncthreads();
    }
    float cscale = 1.f / (sqrtf(ssc) + 1e-8f);
    float tscale = 1.f / fmaxf(sqrtf(sst), 1e-12f);
    float s = dotp * cscale * tscale * (1.f / 0.07f);
    s = fminf(fmaxf(s, -100.f), 100.f);
    float m = s;
    #pragma unroll
    for (int off = 1; off < 16; off <<= 1) m = fmaxf(m, __shfl_xor(m, off, 64));
    float e = expf(s - m);
    #pragma unroll
    for (int off = 1; off < 16; off <<= 1) e += __shfl_xor(e, off, 64);
    float lse = m + logf(e);
    float sd = __shfl(s, ((i & 3) << 4) | i, 64);
    if (j == 0) rowsum[i] = lse - sd;
    __syncthreads();
    if (tid == 0) {
      float acc = 0.f;
      #pragma unroll
      for (int r = 0; r < 16; r++) acc += rowsum[r];
      f[TP_BASE + b] = acc;
    }
    return;
  }

  // ================= CLS path (one block) =================
  {
    float val = 0.f;
    for (int i = tid; i < B; i += 256) {
      float x[7];
      #pragma unroll
      for (int c = 0; c < 7; c++) x[c] = logits[i * 7 + c];
      int pred = 0; float m = x[0];
      #pragma unroll
      for (int c = 1; c < 7; c++) if (x[c] > m) { m = x[c]; pred = c; }
      float s = 0.f;
      #pragma unroll
      for (int c = 0; c < 7; c++) s += expf(x[c] - m);
      float lse = m + logf(s);
      int l = labels[i];
      float logp_l = x[l] - lse;
      float ce = -logp_l;
      float pt = expf(logp_l);
      float focal = powf(1.f - pt, 2.5f);
      float maxp = expf(m - lse);
      float pen = (maxp < 0.7f) ? 1.5f : 1.f;
      val += 0.25f * focal * ce * d_class_w[l] * d_conf[l * 7 + pred] * pen;
    }
    val = wave_sum(val);
    if (lane == 0) part[wave] = val;
    __syncthreads();
    if (tid == 0) f[WS_CLS] = part[0] + part[1] + part[2] + part[3];
  }
}

__launch_bounds__(256)
__global__ void k_final(const float* __restrict__ f, float* __restrict__ out, int B) {
  __shared__ float red[4][4];
  int tid = threadIdx.x, lane = tid & 63, wave = tid >> 6;
  float sp = 0.f, sn = 0.f, cp = 0.f, tx = 0.f;
  const float4* ap4 = (const float4*)(f + AP_BASE);
  for (int t = tid; t < B * 16; t += 256) {
    float4 p = ap4[t];
    sp += p.x; sn += p.y; cp += p.z;
  }
  for (int b = tid; b < B; b += 256) tx += f[TP_BASE + b];
  sp = wave_sum(sp); sn = wave_sum(sn); cp = wave_sum(cp); tx = wave_sum(tx);
  if (lane == 0) {
    red[wave][0] = sp; red[wave][1] = sn; red[wave][2] = cp; red[wave][3] = tx;
  }
  __syncthreads();
  if (tid == 0) {
    float SP = 0.f, SN = 0.f, CP = 0.f, TX = 0.f;
    #pragma unroll
    for (int w = 0; w < 4; w++) {
      SP += red[w][0]; SN += red[w][1]; CP += red[w][2]; TX += red[w][3];
    }
    float total_pairs = (float)B * 16.f;
    float pc = fmaxf(CP, 1.f);
    float ncnt = fmaxf(total_pairs - CP, 1.f);
    float align = SP / pc + 0.1f * SN / ncnt;
    out[0] = f[WS_CLS] / (float)B + 0.3f * align + TX / total_pairs;
  }
}

extern "C" void kernel_launch(void* const* d_in, const int* in_sizes, int n_in,
                              void* d_out, int out_size, void* d_ws, size_t ws_size,
                              hipStream_t stream) {
  const float* dl     = (const float*)d_in[0];
  const float* cs     = (const float*)d_in[1];
  const int*   labels = (const int*)d_in[2];
  const float* ps     = (const float*)d_in[3];
  const float* pf     = (const float*)d_in[4];
  const float* cav    = (const float*)d_in[5];
  const float* wv     = (const float*)d_in[6];
  const float* text   = (const float*)d_in[7];
  const int*   tki    = (const int*)d_in[8];
  float* out = (float*)d_out;
  float* f   = (float*)d_ws;
  int B = in_sizes[0] / 7;
  int swz = (B % 8 == 0) ? 1 : 0;

  hipLaunchKernelGGL(k_fat, dim3(5 * B + 1), dim3(256), 0, stream,
                     cs, labels, ps, pf, cav, wv, text, tki, dl, f, B, swz);
  hipLaunchKernelGGL(k_final, dim3(1), dim3(256), 0, stream, f, out, B);
}

// Round 8
// 59.000 us; speedup vs baseline: 2.5217x; 1.2470x over previous
//
#include <hip/hip_runtime.h>
#include <math.h>

#define P 196
#define C 80
#define D 512
#define CH 128

// ws float-index layout
#define WS_CLS   0
#define AP_BASE  1024    // align partials: (B*16) * 4 floats {sp,sn,cp,-}
#define TP_BASE  40960   // text partials: B floats

__device__ __constant__ float d_class_w[7] = {2.5f, 2.0f, 1.0f, 5.0f, 4.0f, 5.0f, 5.0f};
__device__ __constant__ float d_conf[49] = {
    1,3,2,1,1,2,1,
    3,1,2,1,1,1,1,
    2,2,1,1,1,1,1,
    1,1,1,1,1,1,1,
    1,1,1,1,1,1,2,
    2,1,1,1,1,1,1,
    1,1,1,1,2,1,1};

__device__ __forceinline__ float wave_sum(float v) {
  #pragma unroll
  for (int off = 32; off; off >>= 1) v += __shfl_xor(v, off, 64);
  return v;
}

__device__ __forceinline__ float dot4(float4 a, float4 b) {
  return a.x*b.x + a.y*b.y + a.z*b.z + a.w*b.w;
}

// monotone map: u0 < u1  <=>  f0 < f1 (handles negatives, +-inf)
__device__ __forceinline__ unsigned mono(float v) {
  unsigned u = __float_as_uint(v);
  return u ^ (((unsigned)((int)u >> 31)) | 0x80000000u);
}

#define PIDX(j) ((int)((((j) < 8) ? (pk0 >> (8 * (j))) : (pk1 >> (8 * ((j) - 8)))) & 0xFFull))
#define ROWP(j) (pfb + (size_t)PIDX(j) * (D / 4))

// Fat kernel: blocks [0,B) = text; [B,5B) = align/main; [5B] = cls.
// All block roles fully independent.
__launch_bounds__(256)
__global__ void k_fat(const float* __restrict__ cs, const int* __restrict__ labels,
                      const float* __restrict__ ps, const float* __restrict__ pf,
                      const float* __restrict__ cav, const float* __restrict__ wv,
                      const float* __restrict__ text, const int* __restrict__ tki,
                      const float* __restrict__ logits,
                      float* __restrict__ f, int B, int swz) {
  __shared__ float stx[16][CH + 4];
  __shared__ int sidx[16];
  __shared__ float rowsum[16];
  __shared__ float part[4];

  int bid = blockIdx.x;
  int tid = threadIdx.x, lane = tid & 63, wave = tid >> 6;

  if (bid < B) {
    // ================= TEXT path (1 sample/block, self-computed norms) =====
    int b = bid;
    if (tid < 16) sidx[tid] = tki[b * 16 + tid];
    __syncthreads();
    int i = tid >> 4, j = tid & 15;
    const float* cr = cav + (size_t)sidx[i] * D;
    float dotp = 0.f, ssc = 0.f, sst = 0.f;
    for (int ch = 0; ch < D; ch += CH) {
      // stage 16 rows x CH floats with float4 (512 vec-stores over 256 thr)
      #pragma unroll
      for (int t = tid; t < 16 * (CH / 4); t += 256) {
        int r = t >> 5, d4 = t & 31;
        float4 v = *(const float4*)(text + (size_t)sidx[r] * D + ch + d4 * 4);
        *(float4*)&stx[r][d4 * 4] = v;
      }
      __syncthreads();
      const float4* cr4 = (const float4*)(cr + ch);
      #pragma unroll 8
      for (int d = 0; d < CH; d += 4) {
        float4 a = cr4[d >> 2];
        float4 t4 = *(const float4*)&stx[j][d];
        dotp += dot4(a, t4);
        ssc += dot4(a, a);
        sst += dot4(t4, t4);
      }
      __syncthreads();
    }
    float cscale = 1.f / (sqrtf(ssc) + 1e-8f);
    float tscale = 1.f / fmaxf(sqrtf(sst), 1e-12f);
    float s = dotp * cscale * tscale * (1.f / 0.07f);
    s = fminf(fmaxf(s, -100.f), 100.f);
    float m = s;
    #pragma unroll
    for (int off = 1; off < 16; off <<= 1) m = fmaxf(m, __shfl_xor(m, off, 64));
    float e = expf(s - m);
    #pragma unroll
    for (int off = 1; off < 16; off <<= 1) e += __shfl_xor(e, off, 64);
    float lse = m + logf(e);
    float sd = __shfl(s, ((i & 3) << 4) | i, 64);
    if (j == 0) rowsum[i] = lse - sd;
    __syncthreads();
    if (tid == 0) {
      float acc = 0.f;
      #pragma unroll
      for (int r = 0; r < 16; r++) acc += rowsum[r];
      f[TP_BASE + b] = acc;
    }
    return;
  }

  if (bid < 5 * B) {
    // ================= MAIN (align) path =================
    int mb = bid - B;
    int b, g;
    if (swz) {
      int xcd = mb & 7, rest = mb >> 3;
      g = rest & 3;
      b = (rest >> 2) * 8 + xcd;
    } else {
      b = mb >> 2; g = mb & 3;
    }
    int rank = g * 4 + wave;
    int l = labels[b];

    // w_vote row-l partial (reduced later in the big butterfly)
    float wx = wv[l * C + lane];
    float wy = (lane < C - 64) ? wv[l * C + 64 + lane] : 0.f;
    float wn2 = wx * wx + wy * wy;

    // --- Phase A: set of top-16 concepts (order-free); wave takes rank-th.
    int c;
    {
      float v0 = cs[(size_t)b * C + lane];
      float v1 = (lane < C - 64) ? cs[(size_t)b * C + 64 + lane] : -INFINITY;
      unsigned u0 = mono(v0), u1 = mono(v1);
      unsigned prefix = 0u;
      #pragma unroll
      for (int bit = 31; bit >= 0; --bit) {
        unsigned cand = prefix | (1u << bit);
        int cnt = __popcll(__ballot(u0 >= cand)) + __popcll(__ballot(u1 >= cand));
        if (cnt >= 16) prefix = cand;
      }
      unsigned long long g0 = __ballot(u0 > prefix);
      unsigned long long g1 = __ballot(u1 > prefix);
      unsigned long long e0 = __ballot(u0 == prefix);
      unsigned long long e1 = __ballot(u1 == prefix);
      int take = 16 - __popcll(g0) - __popcll(g1);
      while (take > 0 && e0) { g0 |= e0 & (~e0 + 1ull); e0 &= e0 - 1ull; take--; }
      while (take > 0 && e1) { g1 |= e1 & (~e1 + 1ull); e1 &= e1 - 1ull; take--; }
      int p0 = __popcll(g0);
      if (rank < p0) {
        unsigned long long m = g0;
        int r = rank; while (r--) m &= m - 1ull;
        c = __ffsll(m) - 1;
      } else {
        unsigned long long m = g1;
        int r = rank - p0; while (r--) m &= m - 1ull;
        c = 64 + __ffsll(m) - 1;
      }
    }

    // --- Phase B1: top-16 patch SET for column c via the same bit-search.
    unsigned long long pk0 = 0ull, pk1 = 0ull;
    {
      const float* col = ps + (size_t)b * P * C + c;
      float v0 = col[(size_t)lane * C];
      float v1 = col[(size_t)(64 + lane) * C];
      float v2 = col[(size_t)(128 + lane) * C];
      float v3 = (lane < P - 192) ? col[(size_t)(192 + lane) * C] : -INFINITY;
      unsigned u0 = mono(v0), u1 = mono(v1), u2 = mono(v2), u3 = mono(v3);
      unsigned prefix = 0u;
      #pragma unroll
      for (int bit = 31; bit >= 0; --bit) {
        unsigned cand = prefix | (1u << bit);
        int cnt = __popcll(__ballot(u0 >= cand)) + __popcll(__ballot(u1 >= cand))
                + __popcll(__ballot(u2 >= cand)) + __popcll(__ballot(u3 >= cand));
        if (cnt >= 16) prefix = cand;
      }
      unsigned long long s0 = __ballot(u0 > prefix);
      unsigned long long s1 = __ballot(u1 > prefix);
      unsigned long long s2 = __ballot(u2 > prefix);
      unsigned long long s3 = __ballot(u3 > prefix);
      unsigned long long e0 = __ballot(u0 == prefix);
      unsigned long long e1 = __ballot(u1 == prefix);
      unsigned long long e2 = __ballot(u2 == prefix);
      unsigned long long e3 = __ballot(u3 == prefix);
      int take = 16 - __popcll(s0) - __popcll(s1) - __popcll(s2) - __popcll(s3);
      while (take > 0 && e0) { s0 |= e0 & (~e0 + 1ull); e0 &= e0 - 1ull; take--; }
      while (take > 0 && e1) { s1 |= e1 & (~e1 + 1ull); e1 &= e1 - 1ull; take--; }
      while (take > 0 && e2) { s2 |= e2 & (~e2 + 1ull); e2 &= e2 - 1ull; take--; }
      while (take > 0 && e3) { s3 |= e3 & (~e3 + 1ull); e3 &= e3 - 1ull; take--; }
      int cnt = 0;
      unsigned long long m;
      m = s0; while (m) { unsigned long long p = (unsigned long long)(__ffsll(m) - 1);
        if (cnt < 8) pk0 |= p << (8 * cnt); else pk1 |= p << (8 * (cnt - 8));
        cnt++; m &= m - 1ull; }
      m = s1; while (m) { unsigned long long p = (unsigned long long)(63 + __ffsll(m));
        if (cnt < 8) pk0 |= p << (8 * cnt); else pk1 |= p << (8 * (cnt - 8));
        cnt++; m &= m - 1ull; }
      m = s2; while (m) { unsigned long long p = (unsigned long long)(127 + __ffsll(m));
        if (cnt < 8) pk0 |= p << (8 * cnt); else pk1 |= p << (8 * (cnt - 8));
        cnt++; m &= m - 1ull; }
      m = s3; while (m) { unsigned long long p = (unsigned long long)(191 + __ffsll(m));
        if (cnt < 8) pk0 |= p << (8 * cnt); else pk1 |= p << (8 * (cnt - 8));
        cnt++; m &= m - 1ull; }
    }

    // --- cav row c: load now so its norm rides the big butterfly
    const float4* crow = (const float4*)(cav + (size_t)c * D);
    float4 c0 = crow[lane], c1 = crow[64 + lane];
    float nr2 = dot4(c0, c0) + dot4(c1, c1);

    // --- Phase B2 pass 1: stream all 16 rows, per-lane norm partials only
    const float4* pfb = (const float4*)(pf + (size_t)b * P * D);
    float ssl[16];
    #pragma unroll
    for (int j = 0; j < 8; j++) {
      const float4* row = ROWP(j);
      float4 r0 = row[lane], r1 = row[64 + lane];
      ssl[j] = dot4(r0, r0) + dot4(r1, r1);
    }
    #pragma unroll
    for (int j = 8; j < 16; j++) {
      const float4* row = ROWP(j);
      float4 r0 = row[lane], r1 = row[64 + lane];
      ssl[j] = dot4(r0, r0) + dot4(r1, r1);
    }

    // --- one butterfly reduces 16 row-norms + cav-norm + wv-norm (18-wide)
    #pragma unroll
    for (int off = 32; off; off >>= 1) {
      #pragma unroll
      for (int j = 0; j < 16; j++) ssl[j] += __shfl_xor(ssl[j], off, 64);
      nr2 += __shfl_xor(nr2, off, 64);
      wn2 += __shfl_xor(wn2, off, 64);
    }
    #pragma unroll
    for (int j = 0; j < 16; j++) ssl[j] = 1.f / fmaxf(sqrtf(ssl[j]), 1e-12f);

    // --- Phase B2 pass 2: re-read rows (L2-hot) and accumulate scaled mean
    float4 a0 = make_float4(0, 0, 0, 0), a1 = make_float4(0, 0, 0, 0);
    #pragma unroll
    for (int j = 0; j < 16; j++) {
      const float4* row = ROWP(j);
      float4 r0 = row[lane], r1 = row[64 + lane];
      float sc = ssl[j];
      a0.x += sc * r0.x; a0.y += sc * r0.y; a0.z += sc * r0.z; a0.w += sc * r0.w;
      a1.x += sc * r1.x; a1.y += sc * r1.y; a1.z += sc * r1.z; a1.w += sc * r1.w;
    }
    const float inv16 = 1.f / 16.f;
    a0.x *= inv16; a0.y *= inv16; a0.z *= inv16; a0.w *= inv16;
    a1.x *= inv16; a1.y *= inv16; a1.z *= inv16; a1.w *= inv16;

    // --- epilogue: cosine vs cav row c (2-value reduction only)
    {
      float numr = dot4(a0, c0) + dot4(a1, c1);
      float nm = dot4(a0, a0) + dot4(a1, a1);
      #pragma unroll
      for (int off = 1; off < 64; off <<= 1) {
        numr += __shfl_xor(numr, off, 64);
        nm += __shfl_xor(nm, off, 64);
      }
      if (lane == 0) {
        float n = sqrtf(nr2);
        float csc = 1.f / (n + 1e-8f);
        float num = numr * csc;
        float ncn = n * csc;
        float sim = num / fmaxf(sqrtf(nm) * ncn, 1e-8f);
        float wvs = 1.f / fmaxf(sqrtf(wn2), 1e-12f);
        float dw = wv[l * C + c] * wvs;
        float sp = 0.f, sn = 0.f, cp = 0.f;
        if (dw > 0.1f) { sp = dw * (1.f - sim); cp = 1.f; }
        else           { sn = 1.f + sim; }
        float* prt = f + AP_BASE + (size_t)(b * 16 + rank) * 4;
        prt[0] = sp; prt[1] = sn; prt[2] = cp;
      }
    }
    return;
  }

  // ================= CLS path (one block) =================
  {
    float val = 0.f;
    for (int i = tid; i < B; i += 256) {
      float x[7];
      #pragma unroll
      for (int c = 0; c < 7; c++) x[c] = logits[i * 7 + c];
      int pred = 0; float m = x[0];
      #pragma unroll
      for (int c = 1; c < 7; c++) if (x[c] > m) { m = x[c]; pred = c; }
      float s = 0.f;
      #pragma unroll
      for (int c = 0; c < 7; c++) s += expf(x[c] - m);
      float lse = m + logf(s);
      int l = labels[i];
      float logp_l = x[l] - lse;
      float ce = -logp_l;
      float pt = expf(logp_l);
      float focal = powf(1.f - pt, 2.5f);
      float maxp = expf(m - lse);
      float pen = (maxp < 0.7f) ? 1.5f : 1.f;
      val += 0.25f * focal * ce * d_class_w[l] * d_conf[l * 7 + pred] * pen;
    }
    val = wave_sum(val);
    if (lane == 0) part[wave] = val;
    __syncthreads();
    if (tid == 0) f[WS_CLS] = part[0] + part[1] + part[2] + part[3];
  }
}

__launch_bounds__(256)
__global__ void k_final(const float* __restrict__ f, float* __restrict__ out, int B) {
  __shared__ float red[4][4];
  int tid = threadIdx.x, lane = tid & 63, wave = tid >> 6;
  float sp = 0.f, sn = 0.f, cp = 0.f, tx = 0.f;
  const float4* ap4 = (const float4*)(f + AP_BASE);
  for (int t = tid; t < B * 16; t += 256) {
    float4 p = ap4[t];
    sp += p.x; sn += p.y; cp += p.z;
  }
  for (int b = tid; b < B; b += 256) tx += f[TP_BASE + b];
  sp = wave_sum(sp); sn = wave_sum(sn); cp = wave_sum(cp); tx = wave_sum(tx);
  if (lane == 0) {
    red[wave][0] = sp; red[wave][1] = sn; red[wave][2] = cp; red[wave][3] = tx;
  }
  __syncthreads();
  if (tid == 0) {
    float SP = 0.f, SN = 0.f, CP = 0.f, TX = 0.f;
    #pragma unroll
    for (int w = 0; w < 4; w++) {
      SP += red[w][0]; SN += red[w][1]; CP += red[w][2]; TX += red[w][3];
    }
    float total_pairs = (float)B * 16.f;
    float pc = fmaxf(CP, 1.f);
    float ncnt = fmaxf(total_pairs - CP, 1.f);
    float align = SP / pc + 0.1f * SN / ncnt;
    out[0] = f[WS_CLS] / (float)B + 0.3f * align + TX / total_pairs;
  }
}

extern "C" void kernel_launch(void* const* d_in, const int* in_sizes, int n_in,
                              void* d_out, int out_size, void* d_ws, size_t ws_size,
                              hipStream_t stream) {
  const float* dl     = (const float*)d_in[0];
  const float* cs     = (const float*)d_in[1];
  const int*   labels = (const int*)d_in[2];
  const float* ps     = (const float*)d_in[3];
  const float* pf     = (const float*)d_in[4];
  const float* cav    = (const float*)d_in[5];
  const float* wv     = (const float*)d_in[6];
  const float* text   = (const float*)d_in[7];
  const int*   tki    = (const int*)d_in[8];
  float* out = (float*)d_out;
  float* f   = (float*)d_ws;
  int B = in_sizes[0] / 7;
  int swz = (B % 8 == 0) ? 1 : 0;

  hipLaunchKernelGGL(k_fat, dim3(5 * B + 1), dim3(256), 0, stream,
                     cs, labels, ps, pf, cav, wv, text, tki, dl, f, B, swz);
  hipLaunchKernelGGL(k_final, dim3(1), dim3(256), 0, stream, f, out, B);
}